// Round 2
// baseline (711.423 us; speedup 1.0000x reference)
//
#include <hip/hip_runtime.h>
#include <hip/hip_bf16.h>

// Problem constants
#define B_   32
#define C_   256
#define HW_  1024
#define N_   32768      // B_*HW_
#define M_   2000
#define MP_  2048       // M padded (rows >= 2000 are zero)
#define K_   256
#define TN   32         // pixels per workgroup -> grid 1024
#define QPITCH 272      // halves; q tile [32][272], row stride 136 dw (mod 32 = 8)
#define APITCH 2064     // halves; att tile [32][2064], row stride 1032 dw (mod 32 = 8)

typedef __attribute__((ext_vector_type(8))) _Float16 f16x8;
typedef __attribute__((ext_vector_type(8))) short bf16x8;
typedef __attribute__((ext_vector_type(4))) float f32x4;

#define LDS_ATT_BYTES (TN * APITCH * 2)        // 132096 (q tiles alias the front)
#define LDS_SP_OFF    LDS_ATT_BYTES            // float Sp[8][32]
#define LDS_THR_OFF   (LDS_SP_OFF + 8 * 32 * 4)
#define LDS_INV_OFF   (LDS_THR_OFF + 32 * 4)
#define LDS_TOTAL     (LDS_INV_OFF + 32 * 4)   // 133376 B

// ---------------- prep kernels ----------------

// mem*64 -> fp16 hi/lo split, [MP_][K_], zero-padded rows (GEMM1 B, K-major)
__global__ void prep_memS_kernel(const float* __restrict__ mem,
                                 _Float16* __restrict__ mh,
                                 _Float16* __restrict__ ml) {
  int m = blockIdx.x;           // 0..2047
  int c = threadIdx.x;          // 0..255
  float v = (m < M_) ? mem[m * K_ + c] * 64.0f : 0.0f;
  _Float16 h = (_Float16)v;
  mh[m * K_ + c] = h;
  ml[m * K_ + c] = (_Float16)(v - (float)h);
}

// memT[c][m] bf16, zero-padded m>=2000 (GEMM2 B operand, K(=m)-major)
__global__ void prep_memT_kernel(const float* __restrict__ mem,
                                 __hip_bfloat16* __restrict__ memT) {
  __shared__ float t[32][33];
  int m0 = blockIdx.x * 32;     // 64 blocks
  int c0 = blockIdx.y * 32;     // 8 blocks
  int li = threadIdx.x >> 5;    // 0..7
  int lj = threadIdx.x & 31;
#pragma unroll
  for (int it = 0; it < 4; ++it) {
    int m = li + it * 8;
    t[m][lj] = (m0 + m < M_) ? mem[(m0 + m) * K_ + c0 + lj] : 0.0f;
  }
  __syncthreads();
#pragma unroll
  for (int it = 0; it < 4; ++it) {
    int c = li + it * 8;
    memT[(size_t)(c0 + c) * MP_ + m0 + lj] = __float2bfloat16(t[lj][c]);
  }
}

// ---------------- fused main kernel ----------------
// Per WG (32 pixel-rows): fp16-split GEMM1 -> fp32 logits in MFMA accumulators
// -> no-max softmax sum S (register/shuffle/LDS reduce) -> keep iff e > λ·S
// (softmax denominator cancels) -> bf16 e tile in LDS -> att_map store +
// bf16 GEMM2 with 1/Σ(kept e) folded into both epilogues.
__global__ __launch_bounds__(512, 2) void memae_main_kernel(
    const float* __restrict__ x,
    const _Float16* __restrict__ mh,
    const _Float16* __restrict__ ml,
    const __hip_bfloat16* __restrict__ memT,
    float* __restrict__ y,
    float* __restrict__ att_out) {
  extern __shared__ char smem[];
  _Float16* qhi = (_Float16*)smem;                       // [32][QPITCH]
  _Float16* qlo = (_Float16*)(smem + TN * QPITCH * 2);   // [32][QPITCH]
  __hip_bfloat16* att = (__hip_bfloat16*)smem;           // [32][APITCH] (aliases q)
  float* Sp   = (float*)(smem + LDS_SP_OFF);             // [8][32]
  float* thrL = (float*)(smem + LDS_THR_OFF);            // [32]
  float* invS = (float*)(smem + LDS_INV_OFF);            // [32]

  const int tid   = threadIdx.x;
  const int lane  = tid & 63;
  const int wave  = tid >> 6;        // 0..7
  const int row16 = lane & 15;
  const int quad  = lane >> 4;       // 0..3

  const int n0  = blockIdx.x * TN;
  const int b   = n0 >> 10;
  const int hw0 = n0 & 1023;

  // ---- stage q tile: read x[b][c][hw0..hw0+31], split fp32 -> f16 hi+lo ----
  {
    int c = tid >> 1;                 // 0..255
    int h = tid & 1;                  // 0..1 (which 16 hw's)
    const float4* xp = (const float4*)(x + ((size_t)b * C_ + c) * HW_ + hw0 + h * 16);
    float4 v0 = xp[0], v1 = xp[1], v2 = xp[2], v3 = xp[3];
    float v[16] = {v0.x, v0.y, v0.z, v0.w, v1.x, v1.y, v1.z, v1.w,
                   v2.x, v2.y, v2.z, v2.w, v3.x, v3.y, v3.z, v3.w};
#pragma unroll
    for (int j = 0; j < 16; ++j) {
      int n = h * 16 + j;
      _Float16 fh = (_Float16)v[j];
      qhi[n * QPITCH + c] = fh;
      qlo[n * QPITCH + c] = (_Float16)(v[j] - (float)fh);
    }
  }
  __syncthreads();

  // ---- GEMM1: 64*logit[n][m] into acc registers. wave owns m in [wave*256, +256) ----
  f32x4 acc[16][2];
#pragma unroll
  for (int mt = 0; mt < 16; ++mt)
#pragma unroll
    for (int nt = 0; nt < 2; ++nt) acc[mt][nt] = (f32x4){0.f, 0.f, 0.f, 0.f};

  {
    const int abase = row16 * QPITCH + quad * 8;
    const int bbase = (wave * 256 + row16) * K_ + quad * 8;
#pragma unroll
    for (int g = 0; g < 4; ++g) {
#pragma unroll
      for (int ks = 0; ks < 8; ++ks) {
        f16x8 ah0 = *(const f16x8*)(qhi + abase + ks * 32);
        f16x8 ah1 = *(const f16x8*)(qhi + abase + 16 * QPITCH + ks * 32);
        f16x8 al0 = *(const f16x8*)(qlo + abase + ks * 32);
        f16x8 al1 = *(const f16x8*)(qlo + abase + 16 * QPITCH + ks * 32);
#pragma unroll
        for (int i = 0; i < 4; ++i) {
          const int mt = g * 4 + i;
          const int moff = bbase + mt * 16 * K_ + ks * 32;
          f16x8 bh = *(const f16x8*)(mh + moff);
          f16x8 bl = *(const f16x8*)(ml + moff);
          acc[mt][0] = __builtin_amdgcn_mfma_f32_16x16x32_f16(ah0, bh, acc[mt][0], 0, 0, 0);
          acc[mt][1] = __builtin_amdgcn_mfma_f32_16x16x32_f16(ah1, bh, acc[mt][1], 0, 0, 0);
          acc[mt][0] = __builtin_amdgcn_mfma_f32_16x16x32_f16(al0, bh, acc[mt][0], 0, 0, 0);
          acc[mt][1] = __builtin_amdgcn_mfma_f32_16x16x32_f16(al1, bh, acc[mt][1], 0, 0, 0);
          acc[mt][0] = __builtin_amdgcn_mfma_f32_16x16x32_f16(ah0, bl, acc[mt][0], 0, 0, 0);
          acc[mt][1] = __builtin_amdgcn_mfma_f32_16x16x32_f16(ah1, bl, acc[mt][1], 0, 0, 0);
        }
      }
    }
  }

  // ---- e = exp(logit) in-place (no max-sub: scale cancels in all ratios);
  //      per-row sum S via 16-lane shuffle + cross-wave LDS reduce ----
  float rp[2][4] = {{0.f, 0.f, 0.f, 0.f}, {0.f, 0.f, 0.f, 0.f}};
#pragma unroll
  for (int mt = 0; mt < 16; ++mt) {
    const bool pad = (wave == 7) && (mt >= 13);   // m >= 2000
#pragma unroll
    for (int nt = 0; nt < 2; ++nt)
#pragma unroll
      for (int r = 0; r < 4; ++r) {
        float e = pad ? 0.f : __expf(acc[mt][nt][r] * 0.015625f);  // *2^-6 exact
        acc[mt][nt][r] = e;
        rp[nt][r] += e;
      }
  }
#pragma unroll
  for (int off = 8; off >= 1; off >>= 1)
#pragma unroll
    for (int nt = 0; nt < 2; ++nt)
#pragma unroll
      for (int r = 0; r < 4; ++r) rp[nt][r] += __shfl_xor(rp[nt][r], off, 16);
  if (row16 == 0) {
#pragma unroll
    for (int nt = 0; nt < 2; ++nt)
#pragma unroll
      for (int r = 0; r < 4; ++r) Sp[wave * 32 + nt * 16 + quad * 4 + r] = rp[nt][r];
  }
  __syncthreads();

  if (tid < 32) {
    float s = 0.f;
#pragma unroll
    for (int w = 0; w < 8; ++w) s += Sp[w * 32 + tid];
    thrL[tid] = 0.0025f * s;          // keep iff e > lambda * S
  }
  __syncthreads();

  // ---- decisions (fp32, pre-bf16): write kept e (else 0) as bf16 to LDS ----
  float th[2][4], s2[2][4];
#pragma unroll
  for (int nt = 0; nt < 2; ++nt)
#pragma unroll
    for (int r = 0; r < 4; ++r) {
      th[nt][r] = thrL[nt * 16 + quad * 4 + r];
      s2[nt][r] = 0.f;
    }
#pragma unroll
  for (int mt = 0; mt < 16; ++mt) {
    const int m = wave * 256 + mt * 16 + row16;
#pragma unroll
    for (int nt = 0; nt < 2; ++nt)
#pragma unroll
      for (int r = 0; r < 4; ++r) {
        float e = acc[mt][nt][r];
        float v = (e > th[nt][r]) ? e : 0.f;
        s2[nt][r] += v;
        att[(nt * 16 + quad * 4 + r) * APITCH + m] = __float2bfloat16(v);
      }
  }
#pragma unroll
  for (int off = 8; off >= 1; off >>= 1)
#pragma unroll
    for (int nt = 0; nt < 2; ++nt)
#pragma unroll
      for (int r = 0; r < 4; ++r) s2[nt][r] += __shfl_xor(s2[nt][r], off, 16);
  if (row16 == 0) {
#pragma unroll
    for (int nt = 0; nt < 2; ++nt)
#pragma unroll
      for (int r = 0; r < 4; ++r) Sp[wave * 32 + nt * 16 + quad * 4 + r] = s2[nt][r];
  }
  __syncthreads();

  if (tid < 32) {
    float s = 0.f;
#pragma unroll
    for (int w = 0; w < 8; ++w) s += Sp[w * 32 + tid];
    invS[tid] = (s > 0.f) ? (1.0f / s) : 0.f;   // ref: denom=max(sum,1e-12) -> 0
  }
  __syncthreads();

  // ---- att_map store (coalesced: 8 threads x float4 cover one 128B line) ----
  {
    float* ab = att_out + (size_t)b * M_ * HW_ + hw0;
    for (int j = tid; j < M_ * 8; j += 512) {
      int m = j >> 3;
      int g = j & 7;
      float4 v;
      v.x = __bfloat162float(att[(g * 4 + 0) * APITCH + m]) * invS[g * 4 + 0];
      v.y = __bfloat162float(att[(g * 4 + 1) * APITCH + m]) * invS[g * 4 + 1];
      v.z = __bfloat162float(att[(g * 4 + 2) * APITCH + m]) * invS[g * 4 + 2];
      v.w = __bfloat162float(att[(g * 4 + 3) * APITCH + m]) * invS[g * 4 + 3];
      *(float4*)(ab + (size_t)m * HW_ + g * 4) = v;
    }
  }

  // ---- GEMM2: y = (e @ mem) * invS. wave w owns c in [w*32, w*32+32) ----
  {
    f32x4 o[2][2];
#pragma unroll
    for (int i = 0; i < 2; ++i)
#pragma unroll
      for (int j2 = 0; j2 < 2; ++j2) o[i][j2] = (f32x4){0.f, 0.f, 0.f, 0.f};
    const __hip_bfloat16* bt0 = memT + (size_t)(wave * 32 + row16) * MP_ + quad * 8;
    const __hip_bfloat16* bt1 = bt0 + (size_t)16 * MP_;
    const __hip_bfloat16* a0p = att + row16 * APITCH + quad * 8;
    const __hip_bfloat16* a1p = a0p + 16 * APITCH;
    for (int ks = 0; ks < 64; ++ks) {
      bf16x8 a0 = *(const bf16x8*)(a0p + ks * 32);
      bf16x8 a1 = *(const bf16x8*)(a1p + ks * 32);
      bf16x8 b0 = *(const bf16x8*)(bt0 + ks * 32);
      bf16x8 b1 = *(const bf16x8*)(bt1 + ks * 32);
      o[0][0] = __builtin_amdgcn_mfma_f32_16x16x32_bf16(a0, b0, o[0][0], 0, 0, 0);
      o[0][1] = __builtin_amdgcn_mfma_f32_16x16x32_bf16(a0, b1, o[0][1], 0, 0, 0);
      o[1][0] = __builtin_amdgcn_mfma_f32_16x16x32_bf16(a1, b0, o[1][0], 0, 0, 0);
      o[1][1] = __builtin_amdgcn_mfma_f32_16x16x32_bf16(a1, b1, o[1][1], 0, 0, 0);
    }
    float* yb = y + (size_t)b * C_ * HW_ + hw0;
#pragma unroll
    for (int nt = 0; nt < 2; ++nt) {
#pragma unroll
      for (int ct = 0; ct < 2; ++ct) {
        int c = wave * 32 + ct * 16 + row16;
        int nbase = nt * 16 + quad * 4;
        float4 v;
        v.x = o[nt][ct][0] * invS[nbase + 0];
        v.y = o[nt][ct][1] * invS[nbase + 1];
        v.z = o[nt][ct][2] * invS[nbase + 2];
        v.w = o[nt][ct][3] * invS[nbase + 3];
        *(float4*)(yb + (size_t)c * HW_ + nbase) = v;
      }
    }
  }
}

// ---------------- host ----------------
extern "C" void kernel_launch(void* const* d_in, const int* in_sizes, int n_in,
                              void* d_out, int out_size, void* d_ws, size_t ws_size,
                              hipStream_t stream) {
  const float* x   = (const float*)d_in[0];      // [32,256,32,32]
  const float* mem = (const float*)d_in[1];      // [2000,256]
  float* y       = (float*)d_out;                              // 8388608 floats
  float* att_out = (float*)d_out + (size_t)B_ * C_ * HW_;      // 65536000 floats

  char* ws = (char*)d_ws;
  _Float16* mh = (_Float16*)ws;                                  // 1 MB
  _Float16* ml = (_Float16*)(ws + (size_t)1024 * 1024);          // 1 MB
  __hip_bfloat16* memT = (__hip_bfloat16*)(ws + (size_t)2 * 1024 * 1024);  // 1 MB

  (void)hipFuncSetAttribute((const void*)memae_main_kernel,
                            hipFuncAttributeMaxDynamicSharedMemorySize, LDS_TOTAL);

  prep_memS_kernel<<<dim3(MP_), dim3(K_), 0, stream>>>(mem, mh, ml);
  prep_memT_kernel<<<dim3(MP_ / 32, K_ / 32), dim3(256), 0, stream>>>(mem, memT);
  memae_main_kernel<<<dim3(N_ / TN), dim3(512), LDS_TOTAL, stream>>>(
      x, mh, ml, memT, y, att_out);
}

// Round 3
// 700.089 us; speedup vs baseline: 1.0162x; 1.0162x over previous
//
#include <hip/hip_runtime.h>
#include <hip/hip_bf16.h>

// Problem constants
#define B_   32
#define C_   256
#define HW_  1024
#define N_   32768      // B_*HW_
#define M_   2000
#define MP_  2048       // M padded (rows >= 2000 are zero)
#define K_   256
#define TN   32         // pixels per workgroup -> grid 1024
#define QPITCH 272      // halves; q tile [32][272]
#define APITCH 2068     // halves; att tile [32][2068]; quad row-stride ≡ 8 mod 32 -> 2-way (free)

typedef __attribute__((ext_vector_type(8))) _Float16 f16x8;
typedef __attribute__((ext_vector_type(8))) short bf16x8;
typedef __attribute__((ext_vector_type(4))) float f32x4;

#define LDS_ATT_BYTES (TN * APITCH * 2)        // 132352 (q tiles alias the front)
#define LDS_SP_OFF    LDS_ATT_BYTES            // float Sp[8][32]
#define LDS_THR_OFF   (LDS_SP_OFF + 8 * 32 * 4)
#define LDS_INV_OFF   (LDS_THR_OFF + 32 * 4)
#define LDS_TOTAL     (LDS_INV_OFF + 32 * 4)   // 133632 B

// ---------------- prep kernels ----------------

// mem*64 -> fp16 hi/lo split, [MP_][K_], zero-padded rows (GEMM1 B, K-major)
__global__ void prep_memS_kernel(const float* __restrict__ mem,
                                 _Float16* __restrict__ mh,
                                 _Float16* __restrict__ ml) {
  int m = blockIdx.x;           // 0..2047
  int c = threadIdx.x;          // 0..255
  float v = (m < M_) ? mem[m * K_ + c] * 64.0f : 0.0f;
  _Float16 h = (_Float16)v;
  mh[m * K_ + c] = h;
  ml[m * K_ + c] = (_Float16)(v - (float)h);
}

// memT[c][m] bf16, zero-padded m>=2000 (GEMM2 B operand, K(=m)-major)
__global__ void prep_memT_kernel(const float* __restrict__ mem,
                                 __hip_bfloat16* __restrict__ memT) {
  __shared__ float t[32][33];
  int m0 = blockIdx.x * 32;     // 64 blocks
  int c0 = blockIdx.y * 32;     // 8 blocks
  int li = threadIdx.x >> 5;    // 0..7
  int lj = threadIdx.x & 31;
#pragma unroll
  for (int it = 0; it < 4; ++it) {
    int m = li + it * 8;
    t[m][lj] = (m0 + m < M_) ? mem[(m0 + m) * K_ + c0 + lj] : 0.0f;
  }
  __syncthreads();
#pragma unroll
  for (int it = 0; it < 4; ++it) {
    int c = li + it * 8;
    memT[(size_t)(c0 + c) * MP_ + m0 + lj] = __float2bfloat16(t[lj][c]);
  }
}

// ---------------- fused main kernel ----------------
// Per WG (32 pixel-rows): fp16-split GEMM1 -> fp32 logits in MFMA accumulators
// -> softmax sum S (shuffle+LDS reduce) -> keep iff e > λ·S (softmax denom
// cancels) -> bf16 e tile in LDS (GEMM2 A) -> fused loop: GEMM2 k-chunks
// interleaved with direct-from-register fp32 att_map stores.
__global__ __launch_bounds__(512, 2) void memae_main_kernel(
    const float* __restrict__ x,
    const _Float16* __restrict__ mh,
    const _Float16* __restrict__ ml,
    const __hip_bfloat16* __restrict__ memT,
    float* __restrict__ y,
    float* __restrict__ att_out) {
  extern __shared__ char smem[];
  _Float16* qhi = (_Float16*)smem;                       // [32][QPITCH]
  _Float16* qlo = (_Float16*)(smem + TN * QPITCH * 2);   // [32][QPITCH]
  __hip_bfloat16* att = (__hip_bfloat16*)smem;           // [32][APITCH] (aliases q)
  float* Sp   = (float*)(smem + LDS_SP_OFF);             // [8][32]
  float* thrL = (float*)(smem + LDS_THR_OFF);            // [32]
  float* invS = (float*)(smem + LDS_INV_OFF);            // [32]

  const int tid   = threadIdx.x;
  const int lane  = tid & 63;
  const int wave  = tid >> 6;        // 0..7
  const int row16 = lane & 15;
  const int quad  = lane >> 4;       // 0..3

  const int n0  = blockIdx.x * TN;
  const int b   = n0 >> 10;
  const int hw0 = n0 & 1023;

  // ---- stage q tile: read x[b][c][hw0..hw0+31], split fp32 -> f16 hi+lo ----
  {
    int c = tid >> 1;                 // 0..255
    int h = tid & 1;                  // which 16 hw's
    const float4* xp = (const float4*)(x + ((size_t)b * C_ + c) * HW_ + hw0 + h * 16);
    float4 v0 = xp[0], v1 = xp[1], v2 = xp[2], v3 = xp[3];
    float v[16] = {v0.x, v0.y, v0.z, v0.w, v1.x, v1.y, v1.z, v1.w,
                   v2.x, v2.y, v2.z, v2.w, v3.x, v3.y, v3.z, v3.w};
#pragma unroll
    for (int j = 0; j < 16; ++j) {
      int n = h * 16 + j;
      _Float16 fh = (_Float16)v[j];
      qhi[n * QPITCH + c] = fh;
      qlo[n * QPITCH + c] = (_Float16)(v[j] - (float)fh);
    }
  }
  __syncthreads();

  // ---- GEMM1: 64*logit[n][m] into acc. wave owns m in [wave*256, +256) ----
  f32x4 acc[16][2];
#pragma unroll
  for (int mt = 0; mt < 16; ++mt)
#pragma unroll
    for (int nt = 0; nt < 2; ++nt) acc[mt][nt] = (f32x4){0.f, 0.f, 0.f, 0.f};

  {
    const int abase = row16 * QPITCH + quad * 8;
    const int bbase = (wave * 256 + row16) * K_ + quad * 8;
#pragma unroll
    for (int g = 0; g < 4; ++g) {
#pragma unroll
      for (int ks = 0; ks < 8; ++ks) {
        f16x8 ah0 = *(const f16x8*)(qhi + abase + ks * 32);
        f16x8 ah1 = *(const f16x8*)(qhi + abase + 16 * QPITCH + ks * 32);
        f16x8 al0 = *(const f16x8*)(qlo + abase + ks * 32);
        f16x8 al1 = *(const f16x8*)(qlo + abase + 16 * QPITCH + ks * 32);
        f16x8 bh[4], bl[4];                      // batch loads ahead of MFMAs
#pragma unroll
        for (int i = 0; i < 4; ++i) {
          const int moff = bbase + (g * 4 + i) * 16 * K_ + ks * 32;
          bh[i] = *(const f16x8*)(mh + moff);
          bl[i] = *(const f16x8*)(ml + moff);
        }
#pragma unroll
        for (int i = 0; i < 4; ++i) {
          const int mt = g * 4 + i;
          acc[mt][0] = __builtin_amdgcn_mfma_f32_16x16x32_f16(ah0, bh[i], acc[mt][0], 0, 0, 0);
          acc[mt][1] = __builtin_amdgcn_mfma_f32_16x16x32_f16(ah1, bh[i], acc[mt][1], 0, 0, 0);
          acc[mt][0] = __builtin_amdgcn_mfma_f32_16x16x32_f16(al0, bh[i], acc[mt][0], 0, 0, 0);
          acc[mt][1] = __builtin_amdgcn_mfma_f32_16x16x32_f16(al1, bh[i], acc[mt][1], 0, 0, 0);
          acc[mt][0] = __builtin_amdgcn_mfma_f32_16x16x32_f16(ah0, bl[i], acc[mt][0], 0, 0, 0);
          acc[mt][1] = __builtin_amdgcn_mfma_f32_16x16x32_f16(ah1, bl[i], acc[mt][1], 0, 0, 0);
        }
      }
    }
  }

  // ---- e = exp(logit) in-place; per-row sum S (shuffle + LDS reduce) ----
  float rp[2][4] = {{0.f, 0.f, 0.f, 0.f}, {0.f, 0.f, 0.f, 0.f}};
#pragma unroll
  for (int mt = 0; mt < 16; ++mt) {
    const bool pad = (wave == 7) && (mt >= 13);   // m >= 2000
#pragma unroll
    for (int nt = 0; nt < 2; ++nt)
#pragma unroll
      for (int r = 0; r < 4; ++r) {
        float e = pad ? 0.f : __expf(acc[mt][nt][r] * 0.015625f);  // *2^-6 exact
        acc[mt][nt][r] = e;
        rp[nt][r] += e;
      }
  }
#pragma unroll
  for (int off = 8; off >= 1; off >>= 1)
#pragma unroll
    for (int nt = 0; nt < 2; ++nt)
#pragma unroll
      for (int r = 0; r < 4; ++r) rp[nt][r] += __shfl_xor(rp[nt][r], off, 16);
  if (row16 == 0) {
#pragma unroll
    for (int nt = 0; nt < 2; ++nt)
#pragma unroll
      for (int r = 0; r < 4; ++r) Sp[wave * 32 + nt * 16 + quad * 4 + r] = rp[nt][r];
  }
  __syncthreads();

  if (tid < 32) {
    float s = 0.f;
#pragma unroll
    for (int w = 0; w < 8; ++w) s += Sp[w * 32 + tid];
    thrL[tid] = 0.0025f * s;          // keep iff e > lambda * S
  }
  __syncthreads();

  // ---- decisions (fp32): kept e stays in acc; bf16 copy to LDS for GEMM2 ----
  float th[2][4], s2[2][4];
#pragma unroll
  for (int nt = 0; nt < 2; ++nt)
#pragma unroll
    for (int r = 0; r < 4; ++r) {
      th[nt][r] = thrL[nt * 16 + quad * 4 + r];
      s2[nt][r] = 0.f;
    }
#pragma unroll
  for (int mt = 0; mt < 16; ++mt) {
    const int m = wave * 256 + mt * 16 + row16;
#pragma unroll
    for (int nt = 0; nt < 2; ++nt)
#pragma unroll
      for (int r = 0; r < 4; ++r) {
        float e = acc[mt][nt][r];
        float v = (e > th[nt][r]) ? e : 0.f;
        acc[mt][nt][r] = v;
        s2[nt][r] += v;
        att[(nt * 16 + quad * 4 + r) * APITCH + m] = __float2bfloat16(v);
      }
  }
#pragma unroll
  for (int off = 8; off >= 1; off >>= 1)
#pragma unroll
    for (int nt = 0; nt < 2; ++nt)
#pragma unroll
      for (int r = 0; r < 4; ++r) s2[nt][r] += __shfl_xor(s2[nt][r], off, 16);
  if (row16 == 0) {
#pragma unroll
    for (int nt = 0; nt < 2; ++nt)
#pragma unroll
      for (int r = 0; r < 4; ++r) Sp[wave * 32 + nt * 16 + quad * 4 + r] = s2[nt][r];
  }
  __syncthreads();

  if (tid < 32) {
    float s = 0.f;
#pragma unroll
    for (int w = 0; w < 8; ++w) s += Sp[w * 32 + tid];
    invS[tid] = (s > 0.f) ? (1.0f / s) : 0.f;   // ref: denom=max(sum,1e-12)
  }
  __syncthreads();

  // ---- fused GEMM2 + att_map stores, 4 k-chunks of 512 ----
  {
    float inv[2][4];
#pragma unroll
    for (int nt = 0; nt < 2; ++nt)
#pragma unroll
      for (int r = 0; r < 4; ++r) inv[nt][r] = invS[nt * 16 + quad * 4 + r];

    f32x4 o[2][2];
#pragma unroll
    for (int i = 0; i < 2; ++i)
#pragma unroll
      for (int j2 = 0; j2 < 2; ++j2) o[i][j2] = (f32x4){0.f, 0.f, 0.f, 0.f};

    const __hip_bfloat16* bt0 = memT + (size_t)(wave * 32 + row16) * MP_ + quad * 8;
    const __hip_bfloat16* bt1 = bt0 + (size_t)16 * MP_;
    const __hip_bfloat16* a0p = att + row16 * APITCH + quad * 8;
    const __hip_bfloat16* a1p = a0p + 16 * APITCH;
    float* ab = att_out + (size_t)b * M_ * HW_ + hw0;

#pragma unroll
    for (int ch = 0; ch < 4; ++ch) {
      // GEMM2 partial over k in [ch*512, ch*512+512)
#pragma unroll
      for (int kk = 0; kk < 16; ++kk) {
        const int ks = ch * 16 + kk;
        bf16x8 a0 = *(const bf16x8*)(a0p + ks * 32);
        bf16x8 a1 = *(const bf16x8*)(a1p + ks * 32);
        bf16x8 b0 = *(const bf16x8*)(bt0 + ks * 32);
        bf16x8 b1 = *(const bf16x8*)(bt1 + ks * 32);
        o[0][0] = __builtin_amdgcn_mfma_f32_16x16x32_bf16(a0, b0, o[0][0], 0, 0, 0);
        o[0][1] = __builtin_amdgcn_mfma_f32_16x16x32_bf16(a0, b1, o[0][1], 0, 0, 0);
        o[1][0] = __builtin_amdgcn_mfma_f32_16x16x32_bf16(a1, b0, o[1][0], 0, 0, 0);
        o[1][1] = __builtin_amdgcn_mfma_f32_16x16x32_bf16(a1, b1, o[1][1], 0, 0, 0);
      }
      // att_map stores for this wave's mt group (fp32, direct from registers)
#pragma unroll
      for (int i = 0; i < 4; ++i) {
        const int mt = ch * 4 + i;
        const int m = wave * 256 + mt * 16 + row16;
        if (m < M_) {
#pragma unroll
          for (int nt = 0; nt < 2; ++nt) {
            float4 v;
            v.x = acc[mt][nt][0] * inv[nt][0];
            v.y = acc[mt][nt][1] * inv[nt][1];
            v.z = acc[mt][nt][2] * inv[nt][2];
            v.w = acc[mt][nt][3] * inv[nt][3];
            *(float4*)(ab + (size_t)m * HW_ + nt * 16 + quad * 4) = v;
          }
        }
      }
    }

    // ---- y epilogue ----
    float* yb = y + (size_t)b * C_ * HW_ + hw0;
#pragma unroll
    for (int nt = 0; nt < 2; ++nt) {
#pragma unroll
      for (int ct = 0; ct < 2; ++ct) {
        int c = wave * 32 + ct * 16 + row16;
        int nbase = nt * 16 + quad * 4;
        float4 v;
        v.x = o[nt][ct][0] * inv[nt][0];
        v.y = o[nt][ct][1] * inv[nt][1];
        v.z = o[nt][ct][2] * inv[nt][2];
        v.w = o[nt][ct][3] * inv[nt][3];
        *(float4*)(yb + (size_t)c * HW_ + nbase) = v;
      }
    }
  }
}

// ---------------- host ----------------
extern "C" void kernel_launch(void* const* d_in, const int* in_sizes, int n_in,
                              void* d_out, int out_size, void* d_ws, size_t ws_size,
                              hipStream_t stream) {
  const float* x   = (const float*)d_in[0];      // [32,256,32,32]
  const float* mem = (const float*)d_in[1];      // [2000,256]
  float* y       = (float*)d_out;                              // 8388608 floats
  float* att_out = (float*)d_out + (size_t)B_ * C_ * HW_;      // 65536000 floats

  char* ws = (char*)d_ws;
  _Float16* mh = (_Float16*)ws;                                  // 1 MB
  _Float16* ml = (_Float16*)(ws + (size_t)1024 * 1024);          // 1 MB
  __hip_bfloat16* memT = (__hip_bfloat16*)(ws + (size_t)2 * 1024 * 1024);  // 1 MB

  (void)hipFuncSetAttribute((const void*)memae_main_kernel,
                            hipFuncAttributeMaxDynamicSharedMemorySize, LDS_TOTAL);

  prep_memS_kernel<<<dim3(MP_), dim3(K_), 0, stream>>>(mem, mh, ml);
  prep_memT_kernel<<<dim3(MP_ / 32, K_ / 32), dim3(256), 0, stream>>>(mem, memT);
  memae_main_kernel<<<dim3(N_ / TN), dim3(512), LDS_TOTAL, stream>>>(
      x, mh, ml, memT, y, att_out);
}